// Round 10
// baseline (216.591 us; speedup 1.0000x reference)
//
#include <hip/hip_runtime.h>
#include <stdint.h>

#define DEV __device__ __forceinline__

typedef __bf16 bf16;
typedef __bf16 bf16x8 __attribute__((ext_vector_type(8)));
typedef unsigned short u16x8 __attribute__((ext_vector_type(8)));
typedef float f32x4 __attribute__((ext_vector_type(4)));
typedef uint32_t u32x4 __attribute__((ext_vector_type(4)));

static constexpr int S = 2048, D = 1024, NH = 16;
// fold 1/sqrt(DK) * log2(e) into Q so softmax runs in exp2 domain
static constexpr float QSCALE = 0.125f * 1.44269504088896340736f;
static constexpr float STHR = 4096.0f;  // partial-sum stability threshold (=2^12)

union BU { u16x8 u; bf16x8 v; };
union PU { u32x4 u; bf16x8 v; };

// raw v_exp_f32 (2^x), bypassing OCML's multi-inst exp2f
DEV float fexp2(float x) { return __builtin_amdgcn_exp2f(x); }

// one-inst pack of 2 f32 -> 2 bf16 (no builtin on gfx950; T12 recipe)
DEV uint32_t pack2(float a, float b) {
  uint32_t r;
  asm("v_cvt_pk_bf16_f32 %0, %1, %2" : "=v"(r) : "v"(a), "v"(b));
  return r;
}
DEV float lo_f(uint32_t v) { union { uint32_t u; float f; } c; c.u = v << 16; return c.f; }
DEV float hi_f(uint32_t v) { union { uint32_t u; float f; } c; c.u = v & 0xffff0000u; return c.f; }

// ---------------- batched f32 -> bf16 convert (7 segments, 1 launch) --------
struct CvtArgs { const float* s[7]; bf16* d[7]; };
__global__ __launch_bounds__(256) void cvt_all(CvtArgs a) {
  int blk = blockIdx.x, seg, rel;
  if (blk < 6144) { seg = blk >> 11; rel = blk & 2047; }
  else { int bb = blk - 6144; seg = 3 + (bb >> 9); rel = bb & 511; }
  int i = rel * 256 + threadIdx.x;
  const float4* p = (const float4*)a.s[seg] + (size_t)i * 2;
  float4 x = p[0], y = p[1];
  u32x4 o;
  o[0] = pack2(x.x, x.y);
  o[1] = pack2(x.z, x.w);
  o[2] = pack2(y.x, y.y);
  o[3] = pack2(y.z, y.w);
  ((u32x4*)a.d[seg])[i] = o;
}

// ---------------- async global->LDS 16B ----------------
DEV void async_copy16(bf16* lds_dst, const bf16* g_src) {
  __builtin_amdgcn_global_load_lds(
      (const __attribute__((address_space(1))) void*)(g_src),
      (__attribute__((address_space(3))) void*)(lds_dst),
      16, 0, 0);
}

// ---------------- proj GEMM: C = A*W^T + bias, 128x128 tile (m97) ----------
struct GArgs {
  const bf16* A[3]; const bf16* W[3]; const float* bias[3];
  bf16* Cb[3]; float scale[3];
};

__global__ __launch_bounds__(256, 2)
void gemm128(GArgs g) {
  constexpr int N = 1024, K = 1024;
  const int z = blockIdx.z;
  const bf16* A = g.A[z];
  const bf16* Bt = g.W[z];
  const float* bias = g.bias[z];
  const float scale = g.scale[z];

  __shared__ bf16 As[128 * 32];
  __shared__ bf16 Bs[128 * 32];
  const int t = threadIdx.x;
  const int w = t >> 6, l = t & 63;
  const int wr = w >> 1, wc = w & 1;
  const int lr = l & 15, lg = l >> 4;
  // XCD-aware swizzle: 256 blocks/z, 8 XCDs -> chunk of 32 per XCD
  const int orig = blockIdx.x + (blockIdx.y << 3);
  const int tl = ((orig & 7) << 5) | (orig >> 3);
  const int m0 = (tl >> 3) * 128, n0 = (tl & 7) * 128;

  f32x4 acc[4][4] = {};

  const int srow = t >> 2, scol = (t & 3) * 8;
  const bf16* Aptr = A + (size_t)(m0 + srow) * K + scol;
  const bf16* Bptr = Bt + (size_t)(n0 + srow) * K + scol;
  bf16* AsDst = &As[w * 512];
  bf16* BsDst = &Bs[w * 512];

  for (int k0 = 0; k0 < K; k0 += 32) {
    async_copy16(AsDst,        Aptr + k0);
    async_copy16(AsDst + 2048, Aptr + (size_t)64 * K + k0);
    async_copy16(BsDst,        Bptr + k0);
    async_copy16(BsDst + 2048, Bptr + (size_t)64 * K + k0);
    __syncthreads();
    bf16x8 af[4], bfr[4];
#pragma unroll
    for (int i = 0; i < 4; i++)
      af[i] = *(const bf16x8*)&As[(wr * 64 + i * 16 + lr) * 32 + lg * 8];
#pragma unroll
    for (int i = 0; i < 4; i++)
      bfr[i] = *(const bf16x8*)&Bs[(wc * 64 + i * 16 + lr) * 32 + lg * 8];
#pragma unroll
    for (int mi = 0; mi < 4; mi++)
#pragma unroll
      for (int ni = 0; ni < 4; ni++)
        acc[mi][ni] = __builtin_amdgcn_mfma_f32_16x16x32_bf16(
            af[mi], bfr[ni], acc[mi][ni], 0, 0, 0);
    __syncthreads();
  }

#pragma unroll
  for (int mi = 0; mi < 4; mi++) {
#pragma unroll
    for (int ni = 0; ni < 4; ni++) {
      int col = n0 + wc * 64 + ni * 16 + lr;
      float bv = bias[col];
#pragma unroll
      for (int r = 0; r < 4; r++) {
        int row = m0 + wr * 64 + mi * 16 + lg * 4 + r;
        uint32_t pk = pack2((acc[mi][ni][r] + bv) * scale, 0.f);
        *(uint16_t*)&g.Cb[z][(size_t)row * N + col] = (uint16_t)pk;
      }
    }
  }
}

// ---------------- out GEMM: f32 out, BM=128 BN=64 ----------------
__global__ __launch_bounds__(256, 2)
void gemm64out(const bf16* __restrict__ A, const bf16* __restrict__ Bt,
               const float* __restrict__ bias, float* __restrict__ Cf) {
  constexpr int N = 1024, K = 1024;
  __shared__ bf16 As[128 * 32];
  __shared__ bf16 Bs[64 * 32];
  const int t = threadIdx.x;
  const int w = t >> 6, l = t & 63;
  const int lr = l & 15, lg = l >> 4;
  const int orig = blockIdx.x + (blockIdx.y << 4);
  const int tl = ((orig & 7) << 6) | (orig >> 3);
  const int m0 = (tl >> 4) * 128, n0 = (tl & 15) * 64;

  f32x4 acc[2][4] = {};

  const int srow = t >> 2, scol = (t & 3) * 8;
  const bf16* Aptr = A + (size_t)(m0 + srow) * K + scol;
  const bf16* Bptr = Bt + (size_t)(n0 + srow) * K + scol;
  bf16* AsDst = &As[w * 512];
  bf16* BsDst = &Bs[w * 512];

  for (int k0 = 0; k0 < K; k0 += 32) {
    async_copy16(AsDst,        Aptr + k0);
    async_copy16(AsDst + 2048, Aptr + (size_t)64 * K + k0);
    async_copy16(BsDst,        Bptr + k0);
    __syncthreads();
    bf16x8 af[2], bfr[4];
#pragma unroll
    for (int i = 0; i < 2; i++)
      af[i] = *(const bf16x8*)&As[(w * 32 + i * 16 + lr) * 32 + lg * 8];
#pragma unroll
    for (int n = 0; n < 4; n++)
      bfr[n] = *(const bf16x8*)&Bs[(n * 16 + lr) * 32 + lg * 8];
#pragma unroll
    for (int mi = 0; mi < 2; mi++)
#pragma unroll
      for (int ni = 0; ni < 4; ni++)
        acc[mi][ni] = __builtin_amdgcn_mfma_f32_16x16x32_bf16(
            af[mi], bfr[ni], acc[mi][ni], 0, 0, 0);
    __syncthreads();
  }

#pragma unroll
  for (int mi = 0; mi < 2; mi++) {
#pragma unroll
    for (int ni = 0; ni < 4; ni++) {
      int col = n0 + ni * 16 + lr;
      float bv = bias[col];
#pragma unroll
      for (int r = 0; r < 4; r++) {
        int row = m0 + w * 32 + mi * 16 + lg * 4 + r;
        Cf[(size_t)row * N + col] = acc[mi][ni][r] + bv;
      }
    }
  }
}

// ---------------- flash attention, 8 waves x 16 q-rows, KVBLK=128 ----------
// 16 iterations of 128-kv tiles: HALF the barriers of the 64-kv version.
// K: global_load_lds, permuted+swizzled source, two 64-row halves per tile,
// double-buffered (32 KB). V^T: [64][128] reg-staged, XOR-swizzled, dbuf
// (32 KB). Swapped QK^T -> P lane-local; fixed-shift softmax (raw v_exp);
// halves processed sequentially to cap live VGPRs.
__global__ __launch_bounds__(512, 4)
void attn_kernel(const bf16* __restrict__ Qp, const bf16* __restrict__ Kp,
                 const bf16* __restrict__ Vp, bf16* __restrict__ Oc) {
  __shared__ uint4 ldsu[4096];  // 64 KB: K dbuf [0,32K), V^T dbuf [32K,64K)
  char* lds = (char*)ldsu;

  const int t = threadIdx.x, w = t >> 6, l = t & 63;
  const int lr = l & 15, lg = l >> 4;
  // XCD swizzle: 512 blocks (16 q-blk x 32 bh) -> 64/XCD = 4 heads' K/V
  const int orig = blockIdx.x + (blockIdx.y << 4);
  const int tl = ((orig & 7) << 6) | (orig >> 3);
  const int qblk = tl & 15, bh = tl >> 4;
  const int b = bh >> 4, h = bh & 15;
  const int q0 = qblk * 128;
  const size_t base = (size_t)b * S * D + (size_t)h * 64;
  const size_t TILE = (size_t)128 * D;

  // Q fragments (B-operand): q row = q0 + w*16 + lr
  bf16x8 qf[2];
  {
    const bf16* qrow = Qp + base + (size_t)(q0 + w * 16 + lr) * D + lg * 8;
    qf[0] = *(const bf16x8*)(qrow);
    qf[1] = *(const bf16x8*)(qrow + 32);
  }

  f32x4 accO[4] = {};
  float mrun = 4.0f, lsum = 0.f;

  // K async source (per half c): LDS byte o = c*8192 + w*1024 + l*16 holds
  // K[c*64 + perm(rho)][seg16*8..+7], rho=(o&8191)>>7.
  const bf16* kptr[2];
#pragma unroll
  for (int c = 0; c < 2; c++) {
    int o = w * 1024 + l * 16;
    int rho = o >> 7;
    int seg16 = ((o & 127) ^ ((rho & 7) << 4)) >> 4;
    int mm = rho >> 4;
    int srow = ((mm & 1) << 5) | (((rho >> 2) & 3) << 3) | ((mm >> 1) << 2) | (rho & 3);
    kptr[c] = Kp + base + (size_t)(c * 64 + srow) * D + seg16 * 8;
  }

  // V staging: thread = (kv pair 2l,2l+1) x (d cols w*8..w*8+7)
  const bf16* Vg = Vp + base + (size_t)(2 * l) * D + w * 8;
  int vwa[8];
#pragma unroll
  for (int j = 0; j < 8; j++) {
    int d = w * 8 + j;
    vwa[j] = 32768 + ((d * 256 + l * 4) ^ ((d & 7) << 4));
  }

  const int rswz = (lr & 7) << 4;

  // ---- prologue: K(0) async; V(0) -> regs
  async_copy16((bf16*)(lds + w * 1024),        kptr[0]);
  async_copy16((bf16*)(lds + 8192 + w * 1024), kptr[1]);
  u16x8 va = *(const u16x8*)(Vg);
  u16x8 vb = *(const u16x8*)(Vg + D);
  __syncthreads();  // K(0) + V(0) loads done
#pragma unroll
  for (int j = 0; j < 8; j++)
    *(uint32_t*)(lds + vwa[j]) = (uint32_t)va[j] | ((uint32_t)vb[j] << 16);
  va = *(const u16x8*)(Vg + TILE);
  vb = *(const u16x8*)(Vg + TILE + D);
  __syncthreads();  // Vt(0) published

  const bf16* kp0 = kptr[0] + TILE;
  const bf16* kp1 = kptr[1] + TILE;
  const bf16* vg2 = Vg + 2 * TILE;

  for (int it = 0; it < 16; ++it) {
    const int cur = (it & 1) * 16384;
    const int nxt = ((it + 1) & 1) * 16384;
    const bool hasN = it < 15, hasN2 = it < 14;

    if (hasN) {  // next K tile (async, zero VGPR)
      async_copy16((bf16*)(lds + nxt + w * 1024),        kp0);
      async_copy16((bf16*)(lds + nxt + 8192 + w * 1024), kp1);
      kp0 += TILE; kp1 += TILE;
    }
    const bf16* pv = hasN2 ? vg2 : (Vp + base);  // V(it+2) loads
    u16x8 ta = *(const u16x8*)(pv);
    u16x8 tb = *(const u16x8*)(pv + D);
    vg2 += TILE;

    // ---- QK^T + exp, one 64-kv half at a time (caps live regs)
    float s = 0.f;
    uint32_t pk[8][2];
#pragma unroll
    for (int hh = 0; hh < 2; hh++) {
      f32x4 sc[4] = {};
#pragma unroll
      for (int ks = 0; ks < 2; ks++) {
        BU kf[4];
#pragma unroll
        for (int m = 0; m < 4; m++)
          kf[m].u = *(const u16x8*)(lds + cur + hh * 8192 +
                     ((((m * 16 + lr) * 128) + ks * 64 + lg * 16) ^ rswz));
        __builtin_amdgcn_s_setprio(1);
#pragma unroll
        for (int m = 0; m < 4; m++)
          sc[m] = __builtin_amdgcn_mfma_f32_16x16x32_bf16(
              kf[m].v, qf[ks], sc[m], 0, 0, 0);
        __builtin_amdgcn_s_setprio(0);
      }
#pragma unroll
      for (int m = 0; m < 4; m++) {
        float p0 = fexp2(sc[m][0] - mrun);
        float p1 = fexp2(sc[m][1] - mrun);
        float p2 = fexp2(sc[m][2] - mrun);
        float p3 = fexp2(sc[m][3] - mrun);
        s += (p0 + p1) + (p2 + p3);
        pk[hh * 4 + m][0] = pack2(p0, p1);
        pk[hh * 4 + m][1] = pack2(p2, p3);
      }
    }

    // ---- stability guard (rare path; unpack-scale-repack)
    if (!__all(s <= STHR)) {
      float pm = 0.f;
#pragma unroll
      for (int m = 0; m < 8; m++)
#pragma unroll
        for (int d2 = 0; d2 < 2; d2++) {
          pm = fmaxf(pm, lo_f(pk[m][d2]));
          pm = fmaxf(pm, hi_f(pk[m][d2]));
        }
      pm = fmaxf(pm, __shfl_xor(pm, 16));
      pm = fmaxf(pm, __shfl_xor(pm, 32));
      float mn = fmaxf(mrun + __log2f(pm), mrun);
      float f = fexp2(mrun - mn);
      mrun = mn;
      s *= f;
      lsum *= f;
#pragma unroll
      for (int m = 0; m < 8; m++)
#pragma unroll
        for (int d2 = 0; d2 < 2; d2++)
          pk[m][d2] = pack2(lo_f(pk[m][d2]) * f, hi_f(pk[m][d2]) * f);
#pragma unroll
      for (int r = 0; r < 4; r++) {
        float a = __shfl(f, (lg << 4) | (lg * 4 + r));
#pragma unroll
        for (int n = 0; n < 4; n++) accO[n][r] *= a;
      }
    }
    lsum += s;

    // ---- publish Vt(it+1) into other buffer
    if (hasN) {
#pragma unroll
      for (int j = 0; j < 8; j++)
        *(uint32_t*)(lds + vwa[j] + nxt) = (uint32_t)va[j] | ((uint32_t)vb[j] << 16);
    }

    // ---- PV: A = P (lane-local), B = V^T tile; K-dim 128 = 4 (hh,ks2) steps
#pragma unroll
    for (int hh = 0; hh < 2; hh++)
#pragma unroll
      for (int ks = 0; ks < 2; ks++) {
        PU pa;
        pa.u[0] = pk[hh * 4 + ks][0];
        pa.u[1] = pk[hh * 4 + ks][1];
        pa.u[2] = pk[hh * 4 + 2 + ks][0];
        pa.u[3] = pk[hh * 4 + 2 + ks][1];
        BU vf[4];
#pragma unroll
        for (int n = 0; n < 4; n++)
          vf[n].u = *(const u16x8*)(lds + 32768 + cur +
                     ((((n * 16 + lr) * 256) + hh * 128 + ks * 64 + lg * 16) ^ rswz));
        __builtin_amdgcn_s_setprio(1);
#pragma unroll
        for (int n = 0; n < 4; n++)
          accO[n] = __builtin_amdgcn_mfma_f32_16x16x32_bf16(
              pa.v, vf[n].v, accO[n], 0, 0, 0);
        __builtin_amdgcn_s_setprio(0);
      }

    va = ta; vb = tb;
    __syncthreads();  // drains K copies + Vt writes; publishes tile it+1
  }

  // ---- epilogue
  lsum += __shfl_xor(lsum, 16);
  lsum += __shfl_xor(lsum, 32);
#pragma unroll
  for (int r = 0; r < 4; r++) {
    float lv = __shfl(lsum, (lg << 4) | (lg * 4 + r));
    float rl = 1.0f / lv;
    int row = q0 + w * 16 + lg * 4 + r;
    bf16* orow = Oc + base + (size_t)row * D;
#pragma unroll
    for (int n = 0; n < 4; n++) {
      uint32_t pkv = pack2(accO[n][r] * rl, 0.f);
      *(uint16_t*)&orow[n * 16 + lr] = (uint16_t)pkv;
    }
  }
}

// ---------------- host ----------------
extern "C" void kernel_launch(void* const* d_in, const int* in_sizes, int n_in,
                              void* d_out, int out_size, void* d_ws, size_t ws_size,
                              hipStream_t stream) {
  const float* q  = (const float*)d_in[0];
  const float* k  = (const float*)d_in[1];
  const float* v  = (const float*)d_in[2];
  const float* Wq = (const float*)d_in[3];
  const float* bq = (const float*)d_in[4];
  const float* Wk = (const float*)d_in[5];
  const float* bk = (const float*)d_in[6];
  const float* Wv = (const float*)d_in[7];
  const float* bv = (const float*)d_in[8];
  const float* Wo = (const float*)d_in[9];
  const float* bo = (const float*)d_in[10];
  float* out = (float*)d_out;

  const int BS = 2 * S;                      // 4096 rows
  const size_t SZ_T = (size_t)BS * D * 2;    // 8 MB
  const size_t SZ_W = (size_t)D * D * 2;     // 2 MB

  char* ws = (char*)d_ws;
  bf16* qb  = (bf16*)(ws);
  bf16* kb  = (bf16*)(ws + SZ_T);
  bf16* vb  = (bf16*)(ws + 2 * SZ_T);
  bf16* Wqb = (bf16*)(ws + 3 * SZ_T);
  bf16* Wkb = (bf16*)(ws + 3 * SZ_T + SZ_W);
  bf16* Wvb = (bf16*)(ws + 3 * SZ_T + 2 * SZ_W);
  bf16* Wob = (bf16*)(ws + 3 * SZ_T + 3 * SZ_W);
  bf16* Qh  = (bf16*)(ws + 3 * SZ_T + 4 * SZ_W);
  bf16* Kh  = (bf16*)(ws + 4 * SZ_T + 4 * SZ_W);
  bf16* Vh  = (bf16*)(ws + 5 * SZ_T + 4 * SZ_W);
  bf16* Oc  = qb;  // qb dead after projections

  CvtArgs ca;
  ca.s[0] = q;  ca.d[0] = qb;
  ca.s[1] = k;  ca.d[1] = kb;
  ca.s[2] = v;  ca.d[2] = vb;
  ca.s[3] = Wq; ca.d[3] = Wqb;
  ca.s[4] = Wk; ca.d[4] = Wkb;
  ca.s[5] = Wv; ca.d[5] = Wvb;
  ca.s[6] = Wo; ca.d[6] = Wob;
  cvt_all<<<dim3(8192), 256, 0, stream>>>(ca);

  GArgs gp = {};
  gp.A[0] = qb; gp.W[0] = Wqb; gp.bias[0] = bq; gp.Cb[0] = Qh; gp.scale[0] = QSCALE;
  gp.A[1] = kb; gp.W[1] = Wkb; gp.bias[1] = bk; gp.Cb[1] = Kh; gp.scale[1] = 1.0f;
  gp.A[2] = vb; gp.W[2] = Wvb; gp.bias[2] = bv; gp.Cb[2] = Vh; gp.scale[2] = 1.0f;
  gemm128<<<dim3(D / 128, BS / 128, 3), 256, 0, stream>>>(gp);

  attn_kernel<<<dim3(S / 128, 2 * NH), 512, 0, stream>>>(Qh, Kh, Vh, Oc);

  gemm64out<<<dim3(D / 64, BS / 128), 256, 0, stream>>>(Oc, Wob, bo, out);
}